// Round 16
// baseline (362.893 us; speedup 1.0000x reference)
//
#include <hip/hip_runtime.h>

#define NKER 84
#define NCH 9
#define SEQ 2048
#define NBATCH 64
#define NDIL 26
#define NFTOT 9996
#define MAXNF 15
#define NSLOT 28
#define NXCD 8
#define WPB 2                    // waves sharing one ybuf (R9 optimum)

// Static MiniRocket config for SEQ_LEN=2048, NUM_FEATURES=10000 (replicates numpy float64 logspace)
static constexpr int DILS[NDIL]   = {1,2,3,4,5,7,8,10,12,14,17,20,25,29,35,42,51,61,73,87,104,125,149,178,213,255};
static constexpr int NFDS[NDIL]   = {15,12,4,4,8,4,4,4,4,4,4,4,4,4,4,4,4,4,3,3,3,3,3,3,3,3};
static constexpr int CBASES[NDIL] = {0,1260,2268,2604,2940,3612,3948,4284,4620,4956,5292,5628,5964,6300,6636,6972,7308,7644,7980,8232,8484,8736,8988,9240,9492,9744};

// 2-float vector with 4-byte alignment: legal at odd dword offsets; compiler
// emits ds_read_b64 (aligned) or ds_read2_b32 (unaligned) — one DS instruction
// for two consecutive taps' elements either way. Lane stride 2 dwords ->
// 2 lanes/bank -> conflict-FREE (m136). Conv reads were never the conflict
// source; the build's b128 stores (stride 4 dwords = 8-way) were.
typedef float f32x2u __attribute__((ext_vector_type(2), aligned(4)));

// Force a (known-uniform) float into an SGPR. Scalar v_fma/v_cmp accept one
// SGPR operand at full rate, so wave-uniform constants (w, bias) cost 0 VGPRs.
// R7+R12: packed VOP3P f32 is a dead end (VGPR-only sources AND half-rate).
__device__ __forceinline__ float uniform_f(float v) {
    return __builtin_bit_cast(float, __builtin_amdgcn_readfirstlane(__builtin_bit_cast(int, v)));
}

// Packed f32 add, all-VGPR operands (build-phase accumulate only).
__device__ __forceinline__ f32x2u pk_add(f32x2u a, f32x2u b) {
    f32x2u d;
    asm("v_pk_add_f32 %0, %1, %2" : "=v"(d) : "v"(a), "v"(b));
    return d;
}

template <int I>
__device__ __forceinline__ void body(const float* __restrict__ kw,
                                     const float* __restrict__ cc,
                                     const float* __restrict__ bias,
                                     float* __restrict__ out,
                                     const float* __restrict__ xb,   // x + b*NCH*SEQ
                                     float* __restrict__ y,          // 8KB ybuf SHARED by both waves
                                     int* __restrict__ cbuf,         // NF-int merge buffer
                                     int b, int slot, int lane, int wv) {
    constexpr int D = DILS[I];
    constexpr int NF = NFDS[I];
    constexpr int P = 4 * D;
    constexpr int PAD1 = I & 1;
    constexpr int CBASE = CBASES[I];
    constexpr int RANGE = SEQ - 2 * P;          // valid-region length (>0 for all D)
    // full-range loop split (compile-time): interior j has all taps in [0, SEQ) for every lane
    constexpr int JLO = (P + 63) / 64;                      // first fully-interior 64-iter
    constexpr int JHI = (SEQ - P - 64) / 64;                // last fully-interior 64-iter (incl)
    constexpr int NI  = (JHI + 1 > JLO) ? (JHI + 1 - JLO) : 0;   // # interior 64-iters
    constexpr int NI2 = NI / 2;                             // 128-el pair-iters
    constexpr bool IBR = (NI & 1) != 0;                     // one bridge 64-iter
    constexpr int JT0 = (JHI + 1 > JLO) ? (JHI + 1) : JLO;  // start of trailing boundary
    // valid-region decomposition: pairs + optional 64-bridge + clamped partial
    constexpr int MV2 = RANGE / 128;
    constexpr int TV1 = (RANGE - MV2 * 128) / 64;           // 0 or 1
    constexpr int REM = RANGE - MV2 * 128 - TV1 * 64;       // 0..63

    const float2* __restrict__ xb2 = (const float2*)xb;     // [NCH][SEQ/2]

    for (int k = slot; k < NKER; k += NSLOT) {
        // barrier A: previous k's conv reads + merge reads are done before
        // this k's build overwrites ybuf (and before wave1 re-writes cbuf).
        __syncthreads();

        // ---- per-kernel config (wave-uniform scalars) ----
        int mb = 0;
        for (int c = 0; c < NCH; ++c)
            if (cc[(I * NCH + c) * NKER + k] != 0.0f) mb |= (1 << c);
        mb = __builtin_amdgcn_readfirstlane(mb);

        int j0 = -1, j1 = -1, j2 = -1, no = 0;
        for (int j = 0; j < 9; ++j) {
            if (kw[k * 9 + j] > 0.0f) {
                if (no == 0) j0 = j; else if (no == 1) j1 = j; else j2 = j;
                ++no;
            }
        }
        j0 = __builtin_amdgcn_readfirstlane(j0);
        j1 = __builtin_amdgcn_readfirstlane(j1);
        j2 = __builtin_amdgcn_readfirstlane(j2);

        // tap weights and bias thresholds: wave-uniform -> SGPRs
        float w[9];
#pragma unroll
        for (int jj = 0; jj < 9; ++jj)
            w[jj] = uniform_f((jj == j0 || jj == j1 || jj == j2) ? 2.0f : -1.0f);

        float bs[NF];
#pragma unroll
        for (int f = 0; f < NF; ++f)
            bs[f] = uniform_f(bias[(I * NKER + k) * MAXNF + f]);

        // ---- build y[t]: wave wv builds half h=wv, float2-INTERLEAVED ----
        // Lane L owns f2-slots {L, 64+L} of each 128-f2 chunk: global loads
        // are two coalesced 8B reads (512B/instr), LDS stores are two
        // ds_write_b64 at lane-stride-2-dwords -> 2 lanes/bank -> conflict-
        // free. (R0-R15's float4 path was lane-stride-4 = 8-way conflict on
        // ds_write_b128 -> the invariant 1.5e7 SQ_LDS_BANK_CONFLICT.)
        // y's final content/layout is byte-identical; conv is untouched.
        {
            const int h = wv;
            f32x2u acc2[2 * (SEQ / 512)];
#pragma unroll
            for (int it = 0; it < 2 * (SEQ / 512); ++it)
                acc2[it] = (f32x2u){0.f, 0.f};
#pragma unroll
            for (int c = 0; c < NCH; ++c) {
                if (mb & (1 << c)) {
#pragma unroll
                    for (int it = 0; it < SEQ / 512; ++it) {
                        float2 vlo = xb2[c * (SEQ / 2) + h * (SEQ / 4) + it * 128 + lane];
                        float2 vhi = xb2[c * (SEQ / 2) + h * (SEQ / 4) + it * 128 + 64 + lane];
                        acc2[2 * it]     = pk_add(acc2[2 * it],     (f32x2u){vlo.x, vlo.y});
                        acc2[2 * it + 1] = pk_add(acc2[2 * it + 1], (f32x2u){vhi.x, vhi.y});
                    }
                }
            }
#pragma unroll
            for (int it = 0; it < SEQ / 512; ++it) {
                ((float2*)y)[h * (SEQ / 4) + it * 128 + lane] =
                    make_float2(acc2[2 * it].x, acc2[2 * it].y);
                ((float2*)y)[h * (SEQ / 4) + it * 128 + 64 + lane] =
                    make_float2(acc2[2 * it + 1].x, acc2[2 * it + 1].y);
            }
        }
        // barrier B: both halves of y visible before conv reads cross-half taps
        __syncthreads();

        // wave-total counters via ballot+popcount (scalar-pipe accumulate)
        int cnt[NF];
#pragma unroll
        for (int f = 0; f < NF; ++f) cnt[f] = 0;

#define MRF_ITER2(TB) { \
            const int e0_ = (TB) + 2 * lane - 4 * D; \
            float CvA = 0.0f, CvB = 0.0f; \
            _Pragma("unroll") \
            for (int jj = 0; jj < 9; ++jj) { \
                f32x2u p_ = *(const f32x2u*)(y + e0_ + jj * D); \
                CvA = __builtin_fmaf(w[jj], p_.x, CvA); \
                CvB = __builtin_fmaf(w[jj], p_.y, CvB); \
            } \
            _Pragma("unroll") \
            for (int f = 0; f < NF; ++f) \
                cnt[f] += __popcll(__ballot(CvA > bs[f])) + __popcll(__ballot(CvB > bs[f])); }

#define MRF_ITER(TB) { \
            const int t_ = (TB) + lane; \
            float Cv = 0.0f; \
            _Pragma("unroll") \
            for (int jj = 0; jj < 9; ++jj) \
                Cv = __builtin_fmaf(w[jj], y[t_ + (jj - 4) * D], Cv); \
            _Pragma("unroll") \
            for (int f = 0; f < NF; ++f) \
                cnt[f] += __popcll(__ballot(Cv > bs[f])); }

        // boundary iter: callers fully unroll -> per-tap window tests fold
#define MRF_MASKED(TB) { \
            const int t_ = (TB) + lane; \
            float Cv = 0.0f; \
            _Pragma("unroll") \
            for (int jj = 0; jj < 9; ++jj) { \
                const int lo_ = (TB) + (jj - 4) * D; \
                if (lo_ >= 0 && lo_ + 63 < SEQ) { \
                    Cv = __builtin_fmaf(w[jj], y[t_ + (jj - 4) * D], Cv); \
                } else if (lo_ + 63 >= 0 && lo_ < SEQ) { \
                    const int u_ = t_ + (jj - 4) * D; \
                    float v_ = y[u_ & (SEQ - 1)]; \
                    v_ = ((unsigned)u_ < (unsigned)SEQ) ? v_ : 0.0f; \
                    Cv = __builtin_fmaf(w[jj], v_, Cv); \
                } \
            } \
            _Pragma("unroll") \
            for (int f = 0; f < NF; ++f) \
                cnt[f] += __popcll(__ballot(Cv > bs[f])); }

        // ---- conv: waves split the t-range into disjoint alternating chunks ----
        if ((k & 1) == PAD1) {
            // full padded range [0, SEQ): masked lead + paired interior + masked trail
#pragma unroll
            for (int j = 0; j < JLO; ++j)
                if (((j >> 1) & 1) == wv) MRF_MASKED(j * 64)
#pragma unroll 2
            for (int a = wv; a < NI2; a += 2) MRF_ITER2(JLO * 64 + a * 128)
            if constexpr (IBR)
                if ((NI2 & 1) == wv) MRF_ITER(JLO * 64 + NI2 * 128)
#pragma unroll
            for (int j = JT0; j < SEQ / 64; ++j)
                if (((j >> 1) & 1) == wv) MRF_MASKED(j * 64)
        } else {
            // valid region [P, SEQ-P): paired main + bridge + clamped partial
#pragma unroll 2
            for (int a = wv; a < MV2; a += 2) MRF_ITER2(P + a * 128)
            if constexpr (TV1)
                if ((MV2 & 1) == wv) MRF_ITER(P + MV2 * 128)
            if constexpr (REM != 0) {
                if (((MV2 + TV1) & 1) == wv) {
                    const int t = P + MV2 * 128 + TV1 * 64 + lane;
                    const int tr = (t < SEQ - P) ? t : (SEQ - P - 1);
                    const float* __restrict__ pb = y + tr - 4 * D;
                    float Cv = 0.0f;
#pragma unroll
                    for (int jj = 0; jj < 9; ++jj)
                        Cv = __builtin_fmaf(w[jj], pb[jj * D], Cv);
                    Cv = (t < SEQ - P) ? Cv : -3.402823466e38f;  // poison -> never > bias
#pragma unroll
                    for (int f = 0; f < NF; ++f)
                        cnt[f] += __popcll(__ballot(Cv > bs[f]));
                }
            }
        }

#undef MRF_ITER2
#undef MRF_ITER
#undef MRF_MASKED

        // ---- merge the two waves' counts, wave0 writes out ----
        if (wv == 1 && lane == 0) {
#pragma unroll
            for (int f = 0; f < NF; ++f) cbuf[f] = cnt[f];
        }
        // barrier C: cbuf visible to wave0
        __syncthreads();
        if (wv == 0 && lane == 0) {
            const bool full = ((k & 1) == PAD1);
            const float invT = full ? (1.0f / (float)SEQ) : (1.0f / (float)RANGE);
            const int pos = full ? ((k - PAD1) >> 1) : (42 + ((k - (1 - PAD1)) >> 1));
            const int colb = CBASE + pos * NF;
#pragma unroll
            for (int f = 0; f < NF; ++f)
                out[(size_t)b * NFTOT + colb + f] = (float)(cnt[f] + cbuf[f]) * invT;
        }
    }
}

// Ledger (rounds 0-16):
//  - R9 (317us) is the structural frontier: WPB=2, 8KB shared ybuf, VGPR=64
//    EXACTLY (granule 16; the 80-bucket costs 25% occ — R12). R10-R15 all
//    regressed or tied: WPB=4 shared (+54% VALU), dbuf pipeline (barriers
//    weren't the cost), paired-k build (x/L2 wasn't the cost), dual R9-units
//    (occupancy did NOT rise — 44% is a scheduler property at this point).
//  - R16 (this): single change vs R9 — float2-interleaved build stores.
//    Bank audit: conv reads are stride-2-dword (free); the build's
//    ds_write_b128 at stride-4-dword was the 8-way conflict source matching
//    the invariant 1.5e7 SQ_LDS_BANK_CONFLICT. Falsifiable: counter must
//    drop to <5e6, else the model is wrong and R9's structure is at its
//    latency plateau (VALU 47% / LDS ~50%, both half-busy, dep-chain bound).
//  - Packed f32 FMA dead (R7/R12). Caps: generous (128) only (R1/R10).
extern "C" __global__ void __launch_bounds__(WPB * 64)
__attribute__((amdgpu_num_vgpr(128)))
mrf_kernel(const float* __restrict__ x, const float* __restrict__ kw,
           const float* __restrict__ cc, const float* __restrict__ bias,
           float* __restrict__ out) {
    __shared__ __align__(16) float ybuf[SEQ];   // 8KB, shared by the 2 waves
    __shared__ int cbuf[MAXNF];                 // wave1 -> wave0 count merge

    // XCD-chunked bijective swizzle (proven round 0): XCD x owns a contiguous
    // chunk of (b,i,s) with b slowest -> concurrent blocks on an XCD share ~1-2
    // b values -> x slices stay L2-resident. (R1 measured the alternative:
    // i slowest -> 1.75 GB of L2 misses, 1.7x slower.)
    constexpr int NGRID = NDIL * NBATCH * NSLOT;       // 46592
    constexpr int CHUNK = NGRID / NXCD;                // 5824
    const int blk = (blockIdx.x % NXCD) * CHUNK + blockIdx.x / NXCD;

    const int s = blk % NSLOT;
    const int rest = blk / NSLOT;
    const int i = rest % NDIL;              // dilation index
    const int b = rest / NDIL;              // batch index (slowest)
    const int lane = threadIdx.x & 63;
    // wave id, forced to SGPR so work-split guards are scalar branches
    const int wv = __builtin_amdgcn_readfirstlane((int)(threadIdx.x >> 6));

    const float* xb = x + (size_t)b * (NCH * SEQ);

    switch (i) {
#define MRF_CASE(I) case I: body<I>(kw, cc, bias, out, xb, ybuf, cbuf, b, s, lane, wv); break;
        MRF_CASE(0)  MRF_CASE(1)  MRF_CASE(2)  MRF_CASE(3)  MRF_CASE(4)
        MRF_CASE(5)  MRF_CASE(6)  MRF_CASE(7)  MRF_CASE(8)  MRF_CASE(9)
        MRF_CASE(10) MRF_CASE(11) MRF_CASE(12) MRF_CASE(13) MRF_CASE(14)
        MRF_CASE(15) MRF_CASE(16) MRF_CASE(17) MRF_CASE(18) MRF_CASE(19)
        MRF_CASE(20) MRF_CASE(21) MRF_CASE(22) MRF_CASE(23) MRF_CASE(24)
        MRF_CASE(25)
#undef MRF_CASE
    }
}

extern "C" void kernel_launch(void* const* d_in, const int* in_sizes, int n_in,
                              void* d_out, int out_size, void* d_ws, size_t ws_size,
                              hipStream_t stream) {
    (void)in_sizes; (void)n_in; (void)d_ws; (void)ws_size; (void)out_size;
    const float* x    = (const float*)d_in[0];
    const float* kw   = (const float*)d_in[1];
    const float* cc   = (const float*)d_in[2];
    const float* bias = (const float*)d_in[3];
    float* out = (float*)d_out;

    mrf_kernel<<<dim3(NDIL * NBATCH * NSLOT), dim3(WPB * 64), 0, stream>>>(x, kw, cc, bias, out);
}

// Round 17
// 329.093 us; speedup vs baseline: 1.1027x; 1.1027x over previous
//
#include <hip/hip_runtime.h>

#define NKER 84
#define NCH 9
#define SEQ 2048
#define NBATCH 64
#define NDIL 26
#define NFTOT 9996
#define MAXNF 15
#define NSLOT 28
#define NXCD 8
#define WPB 2                    // waves sharing one ybuf (R9 optimum)

// Static MiniRocket config for SEQ_LEN=2048, NUM_FEATURES=10000 (replicates numpy float64 logspace)
static constexpr int DILS[NDIL]   = {1,2,3,4,5,7,8,10,12,14,17,20,25,29,35,42,51,61,73,87,104,125,149,178,213,255};
static constexpr int NFDS[NDIL]   = {15,12,4,4,8,4,4,4,4,4,4,4,4,4,4,4,4,4,3,3,3,3,3,3,3,3};
static constexpr int CBASES[NDIL] = {0,1260,2268,2604,2940,3612,3948,4284,4620,4956,5292,5628,5964,6300,6636,6972,7308,7644,7980,8232,8484,8736,8988,9240,9492,9744};

// 2-float vector with 4-byte alignment (build-phase accumulate type).
typedef float f32x2u __attribute__((ext_vector_type(2), aligned(4)));

// Force a (known-uniform) float into an SGPR. Scalar v_fma/v_cmp accept one
// SGPR operand at full rate, so wave-uniform constants (w, bias) cost 0 VGPRs.
// R7+R12: packed VOP3P f32 is a dead end (VGPR-only sources AND half-rate).
__device__ __forceinline__ float uniform_f(float v) {
    return __builtin_bit_cast(float, __builtin_amdgcn_readfirstlane(__builtin_bit_cast(int, v)));
}

// Packed f32 add, all-VGPR operands (build-phase accumulate only).
__device__ __forceinline__ f32x2u pk_add(f32x2u a, f32x2u b) {
    f32x2u d;
    asm("v_pk_add_f32 %0, %1, %2" : "=v"(d) : "v"(a), "v"(b));
    return d;
}

template <int I>
__device__ __forceinline__ void body(const float* __restrict__ kw,
                                     const float* __restrict__ cc,
                                     const float* __restrict__ bias,
                                     float* __restrict__ out,
                                     const float* __restrict__ xb,   // x + b*NCH*SEQ
                                     float* __restrict__ y,          // 8KB ybuf SHARED by both waves
                                     int* __restrict__ cbuf,         // NF-int merge buffer
                                     int b, int slot, int lane, int wv) {
    constexpr int D = DILS[I];
    constexpr int NF = NFDS[I];
    constexpr int P = 4 * D;
    constexpr int PAD1 = I & 1;
    constexpr int CBASE = CBASES[I];
    constexpr int RANGE = SEQ - 2 * P;          // valid-region length (>0 for all D)
    // full-range loop split (compile-time): interior j has all taps in [0, SEQ) for every lane
    constexpr int JLO = (P + 63) / 64;                      // first fully-interior 64-iter
    constexpr int JHI = (SEQ - P - 64) / 64;                // last fully-interior 64-iter (incl)
    constexpr int NI  = (JHI + 1 > JLO) ? (JHI + 1 - JLO) : 0;   // # interior 64-iters
    constexpr int NI2 = NI / 2;                             // 128-el pair-iters
    constexpr bool IBR = (NI & 1) != 0;                     // one bridge 64-iter
    constexpr int JT0 = (JHI + 1 > JLO) ? (JHI + 1) : JLO;  // start of trailing boundary
    // valid-region decomposition: pairs + optional 64-bridge + clamped partial
    constexpr int MV2 = RANGE / 128;
    constexpr int TV1 = (RANGE - MV2 * 128) / 64;           // 0 or 1
    constexpr int REM = RANGE - MV2 * 128 - TV1 * 64;       // 0..63

    const float4* __restrict__ xb4 = (const float4*)xb;     // [NCH][SEQ/4]

    for (int k = slot; k < NKER; k += NSLOT) {
        // barrier A: previous k's conv reads + merge reads are done before
        // this k's build overwrites ybuf (and before wave1 re-writes cbuf).
        __syncthreads();

        // ---- per-kernel config (wave-uniform scalars) ----
        int mb = 0;
        for (int c = 0; c < NCH; ++c)
            if (cc[(I * NCH + c) * NKER + k] != 0.0f) mb |= (1 << c);
        mb = __builtin_amdgcn_readfirstlane(mb);

        int j0 = -1, j1 = -1, j2 = -1, no = 0;
        for (int j = 0; j < 9; ++j) {
            if (kw[k * 9 + j] > 0.0f) {
                if (no == 0) j0 = j; else if (no == 1) j1 = j; else j2 = j;
                ++no;
            }
        }
        j0 = __builtin_amdgcn_readfirstlane(j0);
        j1 = __builtin_amdgcn_readfirstlane(j1);
        j2 = __builtin_amdgcn_readfirstlane(j2);

        // tap weights and bias thresholds: wave-uniform -> SGPRs
        float w[9];
#pragma unroll
        for (int jj = 0; jj < 9; ++jj)
            w[jj] = uniform_f((jj == j0 || jj == j1 || jj == j2) ? 2.0f : -1.0f);

        float bs[NF];
#pragma unroll
        for (int f = 0; f < NF; ++f)
            bs[f] = uniform_f(bias[(I * NKER + k) * MAXNF + f]);

        // ---- build y[t]: wave wv builds half h=wv (R9-verbatim float4 path;
        //      R16 proved the build stores were NOT the conflict source) ----
        {
            const int h = wv;
            f32x2u acc2[2 * (SEQ / 512)];
#pragma unroll
            for (int it = 0; it < 2 * (SEQ / 512); ++it)
                acc2[it] = (f32x2u){0.f, 0.f};
#pragma unroll
            for (int c = 0; c < NCH; ++c) {
                if (mb & (1 << c)) {
#pragma unroll
                    for (int it = 0; it < SEQ / 512; ++it) {
                        float4 v = xb4[c * (SEQ / 4) + h * (SEQ / 8) + it * 64 + lane];
                        acc2[2 * it]     = pk_add(acc2[2 * it],     (f32x2u){v.x, v.y});
                        acc2[2 * it + 1] = pk_add(acc2[2 * it + 1], (f32x2u){v.z, v.w});
                    }
                }
            }
#pragma unroll
            for (int it = 0; it < SEQ / 512; ++it)
                ((float4*)y)[h * (SEQ / 8) + it * 64 + lane] =
                    make_float4(acc2[2 * it].x, acc2[2 * it].y,
                                acc2[2 * it + 1].x, acc2[2 * it + 1].y);
        }
        // barrier B: both halves of y visible before conv reads cross-half taps
        __syncthreads();

        // wave-total counters via ballot+popcount (scalar-pipe accumulate)
        int cnt[NF];
#pragma unroll
        for (int f = 0; f < NF; ++f) cnt[f] = 0;

        // 128-el pair iter, COLUMN-SPLIT (R17 single change): lane L handles
        // elements TB+L and TB+64+L (two 64-columns) instead of TB+2L,2L+1.
        // Per tap the two reads are 256B apart -> LLVM merges them into ONE
        // ds_read2_b32 offset0/offset1; each half is lane-stride-1 -> 2
        // lanes/bank -> conflict-free for EVERY dilation and tap parity.
        // (Old interleaved form: odd e0_ -> ds_read2_b32 halves at lane-
        // stride-2 -> 4-way conflict; matched the invariant 1.5e7 counter.)
#define MRF_ITER2(TB) { \
            const int t0_ = (TB) + lane - 4 * D; \
            float CvA = 0.0f, CvB = 0.0f; \
            _Pragma("unroll") \
            for (int jj = 0; jj < 9; ++jj) { \
                const float* __restrict__ pt_ = y + t0_ + jj * D; \
                float pa_ = pt_[0]; \
                float pb_ = pt_[64]; \
                CvA = __builtin_fmaf(w[jj], pa_, CvA); \
                CvB = __builtin_fmaf(w[jj], pb_, CvB); \
            } \
            _Pragma("unroll") \
            for (int f = 0; f < NF; ++f) \
                cnt[f] += __popcll(__ballot(CvA > bs[f])) + __popcll(__ballot(CvB > bs[f])); }

#define MRF_ITER(TB) { \
            const int t_ = (TB) + lane; \
            float Cv = 0.0f; \
            _Pragma("unroll") \
            for (int jj = 0; jj < 9; ++jj) \
                Cv = __builtin_fmaf(w[jj], y[t_ + (jj - 4) * D], Cv); \
            _Pragma("unroll") \
            for (int f = 0; f < NF; ++f) \
                cnt[f] += __popcll(__ballot(Cv > bs[f])); }

        // boundary iter: callers fully unroll -> per-tap window tests fold
#define MRF_MASKED(TB) { \
            const int t_ = (TB) + lane; \
            float Cv = 0.0f; \
            _Pragma("unroll") \
            for (int jj = 0; jj < 9; ++jj) { \
                const int lo_ = (TB) + (jj - 4) * D; \
                if (lo_ >= 0 && lo_ + 63 < SEQ) { \
                    Cv = __builtin_fmaf(w[jj], y[t_ + (jj - 4) * D], Cv); \
                } else if (lo_ + 63 >= 0 && lo_ < SEQ) { \
                    const int u_ = t_ + (jj - 4) * D; \
                    float v_ = y[u_ & (SEQ - 1)]; \
                    v_ = ((unsigned)u_ < (unsigned)SEQ) ? v_ : 0.0f; \
                    Cv = __builtin_fmaf(w[jj], v_, Cv); \
                } \
            } \
            _Pragma("unroll") \
            for (int f = 0; f < NF; ++f) \
                cnt[f] += __popcll(__ballot(Cv > bs[f])); }

        // ---- conv: waves split the t-range into disjoint alternating chunks ----
        if ((k & 1) == PAD1) {
            // full padded range [0, SEQ): masked lead + paired interior + masked trail
#pragma unroll
            for (int j = 0; j < JLO; ++j)
                if (((j >> 1) & 1) == wv) MRF_MASKED(j * 64)
#pragma unroll 2
            for (int a = wv; a < NI2; a += 2) MRF_ITER2(JLO * 64 + a * 128)
            if constexpr (IBR)
                if ((NI2 & 1) == wv) MRF_ITER(JLO * 64 + NI2 * 128)
#pragma unroll
            for (int j = JT0; j < SEQ / 64; ++j)
                if (((j >> 1) & 1) == wv) MRF_MASKED(j * 64)
        } else {
            // valid region [P, SEQ-P): paired main + bridge + clamped partial
#pragma unroll 2
            for (int a = wv; a < MV2; a += 2) MRF_ITER2(P + a * 128)
            if constexpr (TV1)
                if ((MV2 & 1) == wv) MRF_ITER(P + MV2 * 128)
            if constexpr (REM != 0) {
                if (((MV2 + TV1) & 1) == wv) {
                    const int t = P + MV2 * 128 + TV1 * 64 + lane;
                    const int tr = (t < SEQ - P) ? t : (SEQ - P - 1);
                    const float* __restrict__ pb = y + tr - 4 * D;
                    float Cv = 0.0f;
#pragma unroll
                    for (int jj = 0; jj < 9; ++jj)
                        Cv = __builtin_fmaf(w[jj], pb[jj * D], Cv);
                    Cv = (t < SEQ - P) ? Cv : -3.402823466e38f;  // poison -> never > bias
#pragma unroll
                    for (int f = 0; f < NF; ++f)
                        cnt[f] += __popcll(__ballot(Cv > bs[f]));
                }
            }
        }

#undef MRF_ITER2
#undef MRF_ITER
#undef MRF_MASKED

        // ---- merge the two waves' counts, wave0 writes out ----
        if (wv == 1 && lane == 0) {
#pragma unroll
            for (int f = 0; f < NF; ++f) cbuf[f] = cnt[f];
        }
        // barrier C: cbuf visible to wave0
        __syncthreads();
        if (wv == 0 && lane == 0) {
            const bool full = ((k & 1) == PAD1);
            const float invT = full ? (1.0f / (float)SEQ) : (1.0f / (float)RANGE);
            const int pos = full ? ((k - PAD1) >> 1) : (42 + ((k - (1 - PAD1)) >> 1));
            const int colb = CBASE + pos * NF;
#pragma unroll
            for (int f = 0; f < NF; ++f)
                out[(size_t)b * NFTOT + colb + f] = (float)(cnt[f] + cbuf[f]) * invT;
        }
    }
}

// Ledger (rounds 0-17):
//  - R9 (317us) = structural frontier: WPB=2, 8KB shared ybuf, VGPR=64
//    EXACTLY (granule 16; 80-bucket costs 25% occ — R12). R10-R15 all
//    regressed/tied; occupancy pinned ~44% (scheduler property, R15).
//  - R16 falsified the STORE-conflict theory: b128->b64 build stores left
//    SQ_LDS_BANK_CONFLICT at exactly 1.514e7 (and cost 14% via doubled
//    global loads). Conflicts therefore live in the conv READS — the only
//    LDS pattern unchanged in all rounds: odd-aligned ds_read2_b32 halves
//    at lane-stride-2 = 4-way.
//  - R17 (this): column-split ITER2 -> all conv reads lane-stride-1,
//    conflict-free. Crux: counter must drop to <3e6. If dur stays ~317
//    despite the drop, R9's structure is at its latency plateau.
//  - Packed f32 FMA dead (R7/R12). Caps: generous (128) only (R1/R10).
extern "C" __global__ void __launch_bounds__(WPB * 64)
__attribute__((amdgpu_num_vgpr(128)))
mrf_kernel(const float* __restrict__ x, const float* __restrict__ kw,
           const float* __restrict__ cc, const float* __restrict__ bias,
           float* __restrict__ out) {
    __shared__ __align__(16) float ybuf[SEQ];   // 8KB, shared by the 2 waves
    __shared__ int cbuf[MAXNF];                 // wave1 -> wave0 count merge

    // XCD-chunked bijective swizzle (proven round 0): XCD x owns a contiguous
    // chunk of (b,i,s) with b slowest -> concurrent blocks on an XCD share ~1-2
    // b values -> x slices stay L2-resident. (R1 measured the alternative:
    // i slowest -> 1.75 GB of L2 misses, 1.7x slower.)
    constexpr int NGRID = NDIL * NBATCH * NSLOT;       // 46592
    constexpr int CHUNK = NGRID / NXCD;                // 5824
    const int blk = (blockIdx.x % NXCD) * CHUNK + blockIdx.x / NXCD;

    const int s = blk % NSLOT;
    const int rest = blk / NSLOT;
    const int i = rest % NDIL;              // dilation index
    const int b = rest / NDIL;              // batch index (slowest)
    const int lane = threadIdx.x & 63;
    // wave id, forced to SGPR so work-split guards are scalar branches
    const int wv = __builtin_amdgcn_readfirstlane((int)(threadIdx.x >> 6));

    const float* xb = x + (size_t)b * (NCH * SEQ);

    switch (i) {
#define MRF_CASE(I) case I: body<I>(kw, cc, bias, out, xb, ybuf, cbuf, b, s, lane, wv); break;
        MRF_CASE(0)  MRF_CASE(1)  MRF_CASE(2)  MRF_CASE(3)  MRF_CASE(4)
        MRF_CASE(5)  MRF_CASE(6)  MRF_CASE(7)  MRF_CASE(8)  MRF_CASE(9)
        MRF_CASE(10) MRF_CASE(11) MRF_CASE(12) MRF_CASE(13) MRF_CASE(14)
        MRF_CASE(15) MRF_CASE(16) MRF_CASE(17) MRF_CASE(18) MRF_CASE(19)
        MRF_CASE(20) MRF_CASE(21) MRF_CASE(22) MRF_CASE(23) MRF_CASE(24)
        MRF_CASE(25)
#undef MRF_CASE
    }
}

extern "C" void kernel_launch(void* const* d_in, const int* in_sizes, int n_in,
                              void* d_out, int out_size, void* d_ws, size_t ws_size,
                              hipStream_t stream) {
    (void)in_sizes; (void)n_in; (void)d_ws; (void)ws_size; (void)out_size;
    const float* x    = (const float*)d_in[0];
    const float* kw   = (const float*)d_in[1];
    const float* cc   = (const float*)d_in[2];
    const float* bias = (const float*)d_in[3];
    float* out = (float*)d_out;

    mrf_kernel<<<dim3(NDIL * NBATCH * NSLOT), dim3(WPB * 64), 0, stream>>>(x, kw, cc, bias, out);
}